// Round 7
// baseline (526.328 us; speedup 1.0000x reference)
//
#include <hip/hip_runtime.h>
#include <hip/hip_cooperative_groups.h>

namespace cg = cooperative_groups;

// F0=64, F1=128, F2=64, n<=65536, buckets of 128 nodes (nb<=512).
// Single cooperative kernel, 256 blocks x 512 threads, grid.sync between phases.

#define GRID 256
#define BLOCK 512
#define NB2 512

__device__ inline unsigned short f2bf(float f) {
    unsigned int u = __float_as_uint(f);
    unsigned int r = (u + 0x7FFFu + ((u >> 16) & 1u)) >> 16;  // RNE
    return (unsigned short)r;
}
__device__ inline float bf2f(unsigned short h) {
    return __uint_as_float((unsigned int)h << 16);
}

union SMem {
    struct { int hs[NB2], hd[NB2], bs[NB2], bd[NB2]; } pl;   // hist/place
    struct { int wsum[8]; } sc;                              // scan
    struct { int cnt[128]; int cur[128]; int w0tot; } bk;    // per-bucket work
    struct { float W1s[64 * 128]; float As[64 * 68]; float b1s[128]; } g1;
    struct { unsigned short W2u[128 * 64]; float Hs[64 * 132]; } g2;
};

__global__ __launch_bounds__(BLOCK, 2) void fused(
        const float* __restrict__ h, const int* __restrict__ src,
        const int* __restrict__ dst, const float* __restrict__ W1,
        const float* __restrict__ b1, const float* __restrict__ W2,
        const float* __restrict__ b2, float* __restrict__ out,
        float* agg1, unsigned short* H1b, float* norm_src, float* norm_dst,
        int* node_offs, int* gcnt_s, int* gcnt_d, int* offs_s, int* offs_d,
        int* cur_s, int* cur_d, unsigned int* sd, unsigned short* xb,
        unsigned short* y2b, unsigned short* srt, unsigned char* ss,
        int n, int E, int nb) {
    __shared__ SMem sm;
    cg::grid_group grid = cg::this_grid();
    const int tid = threadIdx.x;
    const int bid = blockIdx.x;
    const int gsz = gridDim.x;

    // ---- A0: zero global bucket counters ----
    for (int i = bid * BLOCK + tid; i < 2 * nb; i += gsz * BLOCK) {
        if (i < nb) gcnt_s[i] = 0; else gcnt_d[i - nb] = 0;
    }
    grid.sync();

    // ---- A: bucket histograms (LDS-aggregated) ----
    for (int i = tid; i < nb; i += BLOCK) { sm.pl.hs[i] = 0; sm.pl.hd[i] = 0; }
    __syncthreads();
    {
        int chunk = (E + gsz - 1) / gsz;
        int e0 = bid * chunk;
        int e1 = e0 + chunk; if (e1 > E) e1 = E;
        for (int e = e0 + tid; e < e1; e += BLOCK) {
            atomicAdd(&sm.pl.hs[src[e] >> 7], 1);
            atomicAdd(&sm.pl.hd[dst[e] >> 7], 1);
        }
        __syncthreads();
        for (int i = tid; i < nb; i += BLOCK) {
            if (sm.pl.hs[i]) atomicAdd(&gcnt_s[i], sm.pl.hs[i]);
            if (sm.pl.hd[i]) atomicAdd(&gcnt_d[i], sm.pl.hd[i]);
        }
    }
    grid.sync();

    // ---- B: exclusive scans of both bucket-count arrays (block 0) ----
    if (bid == 0) {
        for (int which = 0; which < 2; ++which) {
            const int* cnt = which ? gcnt_d : gcnt_s;
            int* offs = which ? offs_d : offs_s;
            int* cur  = which ? cur_d  : cur_s;
            int lane = tid & 63, wid = tid >> 6;
            int v = (tid < nb) ? cnt[tid] : 0;
            int incl = v;
            #pragma unroll
            for (int d = 1; d < 64; d <<= 1) {
                int t = __shfl_up(incl, d, 64);
                if (lane >= d) incl += t;
            }
            if (lane == 63) sm.sc.wsum[wid] = incl;
            __syncthreads();
            if (wid == 0) {
                int w = (lane < 8) ? sm.sc.wsum[lane] : 0;
                #pragma unroll
                for (int d = 1; d < 8; d <<= 1) {
                    int t = __shfl_up(w, d, 64);
                    if (lane >= d) w += t;
                }
                if (lane < 8) sm.sc.wsum[lane] = w;
            }
            __syncthreads();
            int excl = (wid ? sm.sc.wsum[wid - 1] : 0) + incl - v;
            if (tid < nb) { offs[tid] = excl; cur[tid] = excl; }
            if (tid == 0) offs[nb] = sm.sc.wsum[7];
            __syncthreads();
        }
    }
    grid.sync();

    // ---- C: bucket placement (per-block LDS hist + one reservation/bucket) ----
    for (int i = tid; i < nb; i += BLOCK) { sm.pl.hs[i] = 0; sm.pl.hd[i] = 0; }
    __syncthreads();
    {
        int chunk = (E + gsz - 1) / gsz;
        int e0 = bid * chunk;
        int e1 = e0 + chunk; if (e1 > E) e1 = E;
        for (int e = e0 + tid; e < e1; e += BLOCK) {
            atomicAdd(&sm.pl.hs[src[e] >> 7], 1);
            atomicAdd(&sm.pl.hd[dst[e] >> 7], 1);
        }
        __syncthreads();
        for (int i = tid; i < nb; i += BLOCK) {
            int v = sm.pl.hs[i]; sm.pl.bs[i] = v ? atomicAdd(&cur_s[i], v) : 0; sm.pl.hs[i] = 0;
            v = sm.pl.hd[i];     sm.pl.bd[i] = v ? atomicAdd(&cur_d[i], v) : 0; sm.pl.hd[i] = 0;
        }
        __syncthreads();
        for (int e = e0 + tid; e < e1; e += BLOCK) {
            int s = src[e], d = dst[e];
            int b1i = s >> 7, b2i = d >> 7;
            int ps = sm.pl.bs[b1i] + atomicAdd(&sm.pl.hs[b1i], 1);
            ss[ps] = (unsigned char)(s & 127);
            int pd = sm.pl.bd[b2i] + atomicAdd(&sm.pl.hd[b2i], 1);
            sd[pd] = ((unsigned int)(d & 127) << 25) | (unsigned int)s;
        }
    }
    grid.sync();

    // ---- D: src-degree + scale/cast x = bf16(h * norm_src) per src-bucket ----
    for (int b = bid; b < nb; b += gsz) {
        if (tid < 128) sm.bk.cnt[tid] = 0;
        __syncthreads();
        int s0 = offs_s[b], s1 = offs_s[b + 1];
        for (int i = s0 + tid; i < s1; i += BLOCK)
            atomicAdd(&sm.bk.cnt[ss[i]], 1);
        __syncthreads();
        int base = b << 7;
        for (int t = tid; t < 128 * 16; t += BLOCK) {
            int r = t >> 4, c4 = (t & 15) * 4;
            int node = base + r;
            if (node < n) {
                int c = sm.bk.cnt[r]; if (c < 1) c = 1;
                float s = 1.0f / sqrtf((float)c);
                if (c4 == 0) norm_src[node] = s;
                float4 v = *(const float4*)(h + (size_t)node * 64 + c4);
                ushort4 o;
                o.x = f2bf(v.x * s); o.y = f2bf(v.y * s);
                o.z = f2bf(v.z * s); o.w = f2bf(v.w * s);
                *(ushort4*)(xb + (size_t)node * 64 + c4) = o;
            }
        }
        __syncthreads();
    }

    // ---- E: per-dst-bucket counting sort -> node CSR + srt(u16) + norm_dst ----
    for (int b = bid; b < nb; b += gsz) {
        if (tid < 128) sm.bk.cnt[tid] = 0;
        __syncthreads();
        int s0 = offs_d[b], s1 = offs_d[b + 1];
        for (int i = s0 + tid; i < s1; i += BLOCK)
            atomicAdd(&sm.bk.cnt[sd[i] >> 25], 1);
        __syncthreads();
        int lane = tid & 63, wid = tid >> 6;
        int v = (tid < 128) ? sm.bk.cnt[tid] : 0;
        int incl = v;
        #pragma unroll
        for (int d = 1; d < 64; d <<= 1) {
            int t = __shfl_up(incl, d, 64);
            if (lane >= d) incl += t;
        }
        if (tid == 63) sm.bk.w0tot = incl;
        __syncthreads();
        if (tid < 128) {
            int excl = incl - v + (wid == 1 ? sm.bk.w0tot : 0);
            sm.bk.cur[tid] = excl;
            int node = (b << 7) + tid;
            if (node < n) {
                node_offs[node] = s0 + excl;
                int c = v; if (c < 1) c = 1;
                norm_dst[node] = 1.0f / sqrtf((float)c);
            }
        }
        if (b == nb - 1 && tid == 0) node_offs[n] = s1;
        __syncthreads();
        for (int i = s0 + tid; i < s1; i += BLOCK) {
            unsigned int e = sd[i];
            int l = (int)(e >> 25);
            int p = s0 + atomicAdd(&sm.bk.cur[l], 1);
            srt[p] = (unsigned short)(e & 0xFFFFu);   // src < 65536
        }
        __syncthreads();
    }
    grid.sync();

    // ---- F: gather1  agg1 = norm_dst * sum(xb[src]) (f32 rows) ----
    {
        int gwave = bid * (BLOCK / 64) + (tid >> 6);
        int nwaves = gsz * (BLOCK / 64);
        int lane = tid & 63;
        int q = lane >> 4;
        int c4 = (lane & 15) * 4;
        for (int node = gwave; node < n; node += nwaves) {
            int a0 = node_offs[node], a1 = node_offs[node + 1];
            float ax = 0.f, ay = 0.f, az = 0.f, aw = 0.f;
            for (int base = a0; base < a1; base += 8) {
                #pragma unroll
                for (int u = 0; u < 2; ++u) {
                    int ei = base + u * 4 + q;
                    int idx = ei < a1 ? ei : a1 - 1;
                    float msk = ei < a1 ? 1.0f : 0.0f;
                    int s = srt[idx];
                    const ushort4 vv = *(const ushort4*)(xb + (size_t)s * 64 + c4);
                    ax = fmaf(bf2f(vv.x), msk, ax);
                    ay = fmaf(bf2f(vv.y), msk, ay);
                    az = fmaf(bf2f(vv.z), msk, az);
                    aw = fmaf(bf2f(vv.w), msk, aw);
                }
            }
            #pragma unroll
            for (int off = 16; off < 64; off <<= 1) {
                ax += __shfl_xor(ax, off, 64);
                ay += __shfl_xor(ay, off, 64);
                az += __shfl_xor(az, off, 64);
                aw += __shfl_xor(aw, off, 64);
            }
            if (q == 0) {
                float s = norm_dst[node];
                float4 r; r.x = ax * s; r.y = ay * s; r.z = az * s; r.w = aw * s;
                *(float4*)(agg1 + (size_t)node * 64 + c4) = r;
            }
        }
    }
    grid.sync();

    // ---- G: gemm1  H1b = bf16(relu(agg1@W1 + b1) * norm_src) ----
    {
        for (int i = tid; i < 64 * 128; i += BLOCK) sm.g1.W1s[i] = W1[i];
        if (tid < 128) sm.g1.b1s[tid] = b1[tid];
        __syncthreads();
        int ntiles = (n + 63) >> 6;
        for (int t = bid; t < ntiles; t += gsz) {
            int m0 = t << 6;
            const float4* Ag = (const float4*)(agg1 + (size_t)m0 * 64);
            for (int idx = tid; idx < 1024; idx += BLOCK) {
                int m = idx >> 4, k4 = (idx & 15) * 4;
                float4 v = make_float4(0.f, 0.f, 0.f, 0.f);
                if (m0 + m < n) v = Ag[idx];
                *(float4*)(sm.g1.As + m * 68 + k4) = v;
            }
            __syncthreads();
            int tx = tid & 15, ty = tid >> 4;   // 8 cols, 2 nodes
            float acc[2][8];
            #pragma unroll
            for (int i = 0; i < 2; ++i)
                #pragma unroll
                for (int j = 0; j < 8; ++j) acc[i][j] = 0.f;
            const float* Ap = sm.g1.As + ty * 2 * 68;
            const float* Wp = sm.g1.W1s + tx * 8;
            for (int k = 0; k < 64; ++k) {
                float a0 = Ap[k];
                float a1v = Ap[68 + k];
                float4 w0 = *(const float4*)(Wp + k * 128);
                float4 w1 = *(const float4*)(Wp + k * 128 + 4);
                acc[0][0] = fmaf(a0, w0.x, acc[0][0]); acc[0][1] = fmaf(a0, w0.y, acc[0][1]);
                acc[0][2] = fmaf(a0, w0.z, acc[0][2]); acc[0][3] = fmaf(a0, w0.w, acc[0][3]);
                acc[0][4] = fmaf(a0, w1.x, acc[0][4]); acc[0][5] = fmaf(a0, w1.y, acc[0][5]);
                acc[0][6] = fmaf(a0, w1.z, acc[0][6]); acc[0][7] = fmaf(a0, w1.w, acc[0][7]);
                acc[1][0] = fmaf(a1v, w0.x, acc[1][0]); acc[1][1] = fmaf(a1v, w0.y, acc[1][1]);
                acc[1][2] = fmaf(a1v, w0.z, acc[1][2]); acc[1][3] = fmaf(a1v, w0.w, acc[1][3]);
                acc[1][4] = fmaf(a1v, w1.x, acc[1][4]); acc[1][5] = fmaf(a1v, w1.y, acc[1][5]);
                acc[1][6] = fmaf(a1v, w1.z, acc[1][6]); acc[1][7] = fmaf(a1v, w1.w, acc[1][7]);
            }
            #pragma unroll
            for (int i = 0; i < 2; ++i) {
                int node = m0 + ty * 2 + i;
                if (node < n) {
                    float s = norm_src[node];
                    unsigned short r[8];
                    #pragma unroll
                    for (int j = 0; j < 8; ++j) {
                        float v = acc[i][j] + sm.g1.b1s[tx * 8 + j];
                        v = v > 0.f ? v : 0.f;
                        r[j] = f2bf(v * s);
                    }
                    unsigned short* o = H1b + (size_t)node * 128 + tx * 8;
                    *(ushort4*)(o)     = make_ushort4(r[0], r[1], r[2], r[3]);
                    *(ushort4*)(o + 4) = make_ushort4(r[4], r[5], r[6], r[7]);
                }
            }
            __syncthreads();
        }
    }
    grid.sync();

    // ---- H: gemm2  y2b = bf16(H1 @ W2) ----
    {
        for (int i = tid; i < 128 * 64; i += BLOCK) sm.g2.W2u[i] = f2bf(W2[i]);
        __syncthreads();
        int ntiles = (n + 63) >> 6;
        for (int t = bid; t < ntiles; t += gsz) {
            int m0 = t << 6;
            const ushort4* Hg = (const ushort4*)(H1b + (size_t)m0 * 128);
            for (int idx = tid; idx < 2048; idx += BLOCK) {
                int m = idx >> 5, k4 = (idx & 31) * 4;
                float4 v = make_float4(0.f, 0.f, 0.f, 0.f);
                if (m0 + m < n) {
                    ushort4 u = Hg[idx];
                    v.x = bf2f(u.x); v.y = bf2f(u.y); v.z = bf2f(u.z); v.w = bf2f(u.w);
                }
                *(float4*)(sm.g2.Hs + m * 132 + k4) = v;
            }
            __syncthreads();
            int tx = tid & 15, ty = tid >> 4;   // 4 cols, 2 nodes
            float acc[2][4];
            #pragma unroll
            for (int i = 0; i < 2; ++i)
                #pragma unroll
                for (int j = 0; j < 4; ++j) acc[i][j] = 0.f;
            const float* Ap = sm.g2.Hs + ty * 2 * 132;
            for (int k = 0; k < 128; ++k) {
                float a0 = Ap[k];
                float a1v = Ap[132 + k];
                ushort4 wu = *(const ushort4*)(sm.g2.W2u + k * 64 + tx * 4);
                float wx = bf2f(wu.x), wy = bf2f(wu.y), wz = bf2f(wu.z), ww = bf2f(wu.w);
                acc[0][0] = fmaf(a0, wx, acc[0][0]); acc[0][1] = fmaf(a0, wy, acc[0][1]);
                acc[0][2] = fmaf(a0, wz, acc[0][2]); acc[0][3] = fmaf(a0, ww, acc[0][3]);
                acc[1][0] = fmaf(a1v, wx, acc[1][0]); acc[1][1] = fmaf(a1v, wy, acc[1][1]);
                acc[1][2] = fmaf(a1v, wz, acc[1][2]); acc[1][3] = fmaf(a1v, ww, acc[1][3]);
            }
            #pragma unroll
            for (int i = 0; i < 2; ++i) {
                int node = m0 + ty * 2 + i;
                if (node < n) {
                    ushort4 o;
                    o.x = f2bf(acc[i][0]); o.y = f2bf(acc[i][1]);
                    o.z = f2bf(acc[i][2]); o.w = f2bf(acc[i][3]);
                    *(ushort4*)(y2b + (size_t)node * 64 + tx * 4) = o;
                }
            }
            __syncthreads();
        }
    }
    grid.sync();

    // ---- I: gather2  out = norm_dst * sum(y2b[src]) + b2 ----
    {
        int gwave = bid * (BLOCK / 64) + (tid >> 6);
        int nwaves = gsz * (BLOCK / 64);
        int lane = tid & 63;
        int q = lane >> 4;
        int c4 = (lane & 15) * 4;
        for (int node = gwave; node < n; node += nwaves) {
            int a0 = node_offs[node], a1 = node_offs[node + 1];
            float ax = 0.f, ay = 0.f, az = 0.f, aw = 0.f;
            for (int base = a0; base < a1; base += 8) {
                #pragma unroll
                for (int u = 0; u < 2; ++u) {
                    int ei = base + u * 4 + q;
                    int idx = ei < a1 ? ei : a1 - 1;
                    float msk = ei < a1 ? 1.0f : 0.0f;
                    int s = srt[idx];
                    const ushort4 vv = *(const ushort4*)(y2b + (size_t)s * 64 + c4);
                    ax = fmaf(bf2f(vv.x), msk, ax);
                    ay = fmaf(bf2f(vv.y), msk, ay);
                    az = fmaf(bf2f(vv.z), msk, az);
                    aw = fmaf(bf2f(vv.w), msk, aw);
                }
            }
            #pragma unroll
            for (int off = 16; off < 64; off <<= 1) {
                ax += __shfl_xor(ax, off, 64);
                ay += __shfl_xor(ay, off, 64);
                az += __shfl_xor(az, off, 64);
                aw += __shfl_xor(aw, off, 64);
            }
            if (q == 0) {
                float s = norm_dst[node];
                const float4 bb = *(const float4*)(b2 + c4);
                float4 r;
                r.x = ax * s + bb.x; r.y = ay * s + bb.y;
                r.z = az * s + bb.z; r.w = aw * s + bb.w;
                *(float4*)(out + (size_t)node * 64 + c4) = r;
            }
        }
    }
}

extern "C" void kernel_launch(void* const* d_in, const int* in_sizes, int n_in,
                              void* d_out, int out_size, void* d_ws, size_t ws_size,
                              hipStream_t stream) {
    const float* h   = (const float*)d_in[0];
    const int*   src = (const int*)d_in[1];
    const int*   dst = (const int*)d_in[2];
    const float* W1  = (const float*)d_in[3];
    const float* b1  = (const float*)d_in[4];
    const float* W2  = (const float*)d_in[5];
    const float* b2  = (const float*)d_in[6];
    float* out = (float*)d_out;

    int n = in_sizes[0] / 64;
    int E = in_sizes[1];
    int nb = (n + 127) >> 7;

    float* ws = (float*)d_ws;
    float* agg1     = ws;                            // [n,64] f32
    float* norm_src = agg1 + (size_t)n * 64;         // [n]
    float* norm_dst = norm_src + n;                  // [n]
    int* node_offs  = (int*)(norm_dst + n);          // [n+1]
    int* gcnt_s = node_offs + n + 1;                 // [nb]
    int* gcnt_d = gcnt_s + nb;                       // [nb]
    int* offs_s = gcnt_d + nb;                       // [nb+1]
    int* offs_d = offs_s + nb + 1;                   // [nb+1]
    int* cur_s  = offs_d + nb + 1;                   // [nb]
    int* cur_d  = cur_s + nb;                        // [nb]
    unsigned int* sd = (unsigned int*)(cur_d + nb);  // [E]
    unsigned short* H1b = (unsigned short*)(sd + E); // [n,128] bf16
    unsigned short* xb  = H1b + (size_t)n * 128;     // [n,64] bf16
    unsigned short* y2b = xb + (size_t)n * 64;       // [n,64] bf16
    unsigned short* srt = y2b + (size_t)n * 64;      // [E] u16
    unsigned char*  ssb = (unsigned char*)(srt + E); // [E] u8

    void* args[] = {
        (void*)&h, (void*)&src, (void*)&dst, (void*)&W1, (void*)&b1,
        (void*)&W2, (void*)&b2, (void*)&out,
        (void*)&agg1, (void*)&H1b, (void*)&norm_src, (void*)&norm_dst,
        (void*)&node_offs, (void*)&gcnt_s, (void*)&gcnt_d, (void*)&offs_s,
        (void*)&offs_d, (void*)&cur_s, (void*)&cur_d, (void*)&sd,
        (void*)&xb, (void*)&y2b, (void*)&srt, (void*)&ssb,
        (void*)&n, (void*)&E, (void*)&nb
    };
    hipLaunchCooperativeKernel((const void*)fused, dim3(GRID), dim3(BLOCK),
                               args, 0, stream);
}

// Round 8
// 198.671 us; speedup vs baseline: 2.6492x; 2.6492x over previous
//
#include <hip/hip_runtime.h>

// F0=64, F1=128, F2=64. n<=65536, buckets of 128 nodes, slotted CSR with
// fixed bucket capacity CAP (no hist/scan passes).
// Pipeline: memset(cnt) -> place_direct -> srcdeg_scale -> bucket_sort ->
//           gather8(xb->agg1) -> gemm1(->H1b bf16) -> gemm2b(->y2b bf16) ->
//           gather8(y2b->out,+b2)

#define NBMAX 512
#define CAPLOG 12
#define CAP (1 << CAPLOG)

__device__ inline unsigned short f2bf(float f) {
    unsigned int u = __float_as_uint(f);
    unsigned int r = (u + 0x7FFFu + ((u >> 16) & 1u)) >> 16;  // RNE
    return (unsigned short)r;
}
__device__ inline float bf2f_lo(unsigned int u) { return __uint_as_float(u << 16); }
__device__ inline float bf2f_hi(unsigned int u) { return __uint_as_float(u & 0xFFFF0000u); }
__device__ inline float bf2f(unsigned short h) {
    return __uint_as_float((unsigned int)h << 16);
}

// One pass over edges: per-block LDS hist -> one global reservation atomic per
// (block,bucket) -> LDS-cursor scatter into slotted bucket arrays.
// src entry: 1B local id. dst entry: (dst&127)<<25 | src.
__global__ __launch_bounds__(256) void place_direct(const int* __restrict__ src,
        const int* __restrict__ dst, int* __restrict__ cnt_s, int* __restrict__ cnt_d,
        unsigned char* __restrict__ ss, unsigned int* __restrict__ sd,
        int n_edges, int nb) {
    __shared__ int hs[NBMAX], hd[NBMAX], bs[NBMAX], bd[NBMAX];
    for (int i = threadIdx.x; i < nb; i += 256) { hs[i] = 0; hd[i] = 0; }
    __syncthreads();
    int chunk = (n_edges + gridDim.x - 1) / gridDim.x;
    int e0 = blockIdx.x * chunk;
    int e1 = e0 + chunk; if (e1 > n_edges) e1 = n_edges;
    for (int e = e0 + (int)threadIdx.x; e < e1; e += 256) {
        atomicAdd(&hs[src[e] >> 7], 1);
        atomicAdd(&hd[dst[e] >> 7], 1);
    }
    __syncthreads();
    for (int i = threadIdx.x; i < nb; i += 256) {
        int v = hs[i]; bs[i] = v ? atomicAdd(&cnt_s[i], v) : 0; hs[i] = 0;
        v = hd[i];     bd[i] = v ? atomicAdd(&cnt_d[i], v) : 0; hd[i] = 0;
    }
    __syncthreads();
    for (int e = e0 + (int)threadIdx.x; e < e1; e += 256) {
        int s = src[e], d = dst[e];
        int sb = s >> 7, db = d >> 7;
        int ps = bs[sb] + atomicAdd(&hs[sb], 1);
        ss[((size_t)sb << CAPLOG) + ps] = (unsigned char)(s & 127);
        int pd = bd[db] + atomicAdd(&hd[db], 1);
        sd[((size_t)db << CAPLOG) + pd] = ((unsigned int)(d & 127) << 25) | (unsigned int)s;
    }
}

// One block per src-bucket: count local ids -> norm_src, then xb = bf16(h*norm).
__global__ __launch_bounds__(256) void srcdeg_scale(const float* __restrict__ h,
        const unsigned char* __restrict__ ss, const int* __restrict__ cnt_s,
        float* __restrict__ norm_src, unsigned short* __restrict__ xb, int n) {
    __shared__ int cnt[128];
    __shared__ float nrm[128];
    const int b = blockIdx.x;
    if (threadIdx.x < 128) cnt[threadIdx.x] = 0;
    __syncthreads();
    int used = cnt_s[b];
    const unsigned char* p = ss + ((size_t)b << CAPLOG);
    for (int i = threadIdx.x; i < used; i += 256) atomicAdd(&cnt[p[i]], 1);
    __syncthreads();
    if (threadIdx.x < 128) {
        int c = cnt[threadIdx.x]; if (c < 1) c = 1;
        float s = 1.0f / sqrtf((float)c);
        nrm[threadIdx.x] = s;
        int node = (b << 7) + (int)threadIdx.x;
        if (node < n) norm_src[node] = s;
    }
    __syncthreads();
    int base = b << 7;
    for (int t = threadIdx.x; t < 128 * 16; t += 256) {
        int r = t >> 4, c4 = (t & 15) << 2;
        int node = base + r;
        if (node < n) {
            float s = nrm[r];
            float4 v = *(const float4*)(h + (size_t)node * 64 + c4);
            ushort4 o;
            o.x = f2bf(v.x * s); o.y = f2bf(v.y * s);
            o.z = f2bf(v.z * s); o.w = f2bf(v.w * s);
            *(ushort4*)(xb + (size_t)node * 64 + c4) = o;
        }
    }
}

// One block per dst-bucket: 128-bin count -> scan -> node_rng (slotted) +
// counting-sorted srt (u16 src ids) + norm_dst.
__global__ __launch_bounds__(256) void bucket_sort(const unsigned int* __restrict__ sd,
        const int* __restrict__ cnt_d, int2* __restrict__ node_rng,
        unsigned short* __restrict__ srt, float* __restrict__ norm_dst, int n) {
    __shared__ int cnt[128], cur[128];
    __shared__ int w0tot;
    const int b = blockIdx.x;
    if (threadIdx.x < 128) cnt[threadIdx.x] = 0;
    __syncthreads();
    int used = cnt_d[b];
    const unsigned int* p = sd + ((size_t)b << CAPLOG);
    for (int i = threadIdx.x; i < used; i += 256) atomicAdd(&cnt[p[i] >> 25], 1);
    __syncthreads();
    int lane = threadIdx.x & 63, wid = threadIdx.x >> 6;
    int v = (threadIdx.x < 128) ? cnt[threadIdx.x] : 0;
    int incl = v;
    #pragma unroll
    for (int d = 1; d < 64; d <<= 1) {
        int t = __shfl_up(incl, d, 64);
        if (lane >= d) incl += t;
    }
    if (threadIdx.x == 63) w0tot = incl;
    __syncthreads();
    if (threadIdx.x < 128) {
        int excl = incl - v + (wid == 1 ? w0tot : 0);
        cur[threadIdx.x] = excl;
        int node = (b << 7) + (int)threadIdx.x;
        if (node < n) {
            int base = b << CAPLOG;
            node_rng[node] = make_int2(base + excl, base + excl + v);
            int c = v; if (c < 1) c = 1;
            norm_dst[node] = 1.0f / sqrtf((float)c);
        }
    }
    __syncthreads();
    for (int i = threadIdx.x; i < used; i += 256) {
        unsigned int e = p[i];
        int l = (int)(e >> 25);
        int pos = atomicAdd(&cur[l], 1);
        srt[((size_t)b << CAPLOG) + pos] = (unsigned short)(e & 0xFFFFu);
    }
}

// One wave per dst node. 8 lanes x bf16x8 (16B dwordx4) cover the 64-wide row;
// 8 lane-groups process 8 edges concurrently, unroll 2 -> 16 edges in flight.
// f32 accumulate, 3-level shfl_xor reduce, lanes 0..7 write the f32 row.
__global__ __launch_bounds__(256) void gather8(const unsigned short* __restrict__ xb,
        const unsigned short* __restrict__ srt, const int2* __restrict__ node_rng,
        const float* __restrict__ nrm, const float* __restrict__ bias,
        float* __restrict__ out, int n_nodes) {
    int node = blockIdx.x * 4 + (threadIdx.x >> 6);
    if (node >= n_nodes) return;
    int lane = threadIdx.x & 63;
    int g  = lane >> 3;         // edge slot 0..7
    int c8 = (lane & 7) * 8;    // column base
    int2 rng = node_rng[node];
    int a0 = rng.x, a1 = rng.y;
    float acc[8];
    #pragma unroll
    for (int j = 0; j < 8; ++j) acc[j] = 0.f;
    for (int base = a0; base < a1; base += 16) {
        #pragma unroll
        for (int u = 0; u < 2; ++u) {
            int ei = base + u * 8 + g;
            int idx = ei < a1 ? ei : a1 - 1;
            float msk = ei < a1 ? 1.0f : 0.0f;
            int s = srt[idx];
            const uint4 v = *(const uint4*)(xb + (size_t)s * 64 + c8);
            acc[0] = fmaf(bf2f_lo(v.x), msk, acc[0]);
            acc[1] = fmaf(bf2f_hi(v.x), msk, acc[1]);
            acc[2] = fmaf(bf2f_lo(v.y), msk, acc[2]);
            acc[3] = fmaf(bf2f_hi(v.y), msk, acc[3]);
            acc[4] = fmaf(bf2f_lo(v.z), msk, acc[4]);
            acc[5] = fmaf(bf2f_hi(v.z), msk, acc[5]);
            acc[6] = fmaf(bf2f_lo(v.w), msk, acc[6]);
            acc[7] = fmaf(bf2f_hi(v.w), msk, acc[7]);
        }
    }
    #pragma unroll
    for (int off = 8; off < 64; off <<= 1) {
        #pragma unroll
        for (int j = 0; j < 8; ++j) acc[j] += __shfl_xor(acc[j], off, 64);
    }
    if (g == 0) {
        float s = nrm[node];
        float r[8];
        #pragma unroll
        for (int j = 0; j < 8; ++j) r[j] = acc[j] * s;
        if (bias) {
            #pragma unroll
            for (int j = 0; j < 8; ++j) r[j] += bias[c8 + j];
        }
        float* o = out + (size_t)node * 64 + c8;
        *(float4*)(o)     = make_float4(r[0], r[1], r[2], r[3]);
        *(float4*)(o + 4) = make_float4(r[4], r[5], r[6], r[7]);
    }
}

// H1b[n,128] = bf16(relu(A[n,64] @ W1[64,128] + b1) * norm_src[node])
__global__ __launch_bounds__(256) void gemm1(const float* __restrict__ A,
        const float* __restrict__ W1, const float* __restrict__ b1,
        const float* __restrict__ norm, unsigned short* __restrict__ H1b, int n_nodes) {
    __shared__ float Ws[64 * 128];
    __shared__ float As[64 * 68];
    __shared__ float b1s[128];
    const int tid = threadIdx.x;
    for (int idx = tid; idx < 64 * 128; idx += 256) Ws[idx] = W1[idx];
    if (tid < 128) b1s[tid] = b1[tid];

    const int m0 = blockIdx.x * 64;
    const float4* Ag = (const float4*)(A + (size_t)m0 * 64);
    #pragma unroll
    for (int i = 0; i < 4; ++i) {
        int idx = tid + i * 256;
        int m = idx >> 4;
        int k4 = (idx & 15) * 4;
        float4 v = make_float4(0.f, 0.f, 0.f, 0.f);
        if (m0 + m < n_nodes) v = Ag[idx];
        *(float4*)(As + m * 68 + k4) = v;
    }
    __syncthreads();

    const int tx = tid & 15;
    const int ty = tid >> 4;
    float acc[4][8];
    #pragma unroll
    for (int i = 0; i < 4; ++i)
        #pragma unroll
        for (int j = 0; j < 8; ++j) acc[i][j] = 0.0f;

    const float* Ap = As + ty * 4 * 68;
    const float* Wp = Ws + tx * 8;
    for (int k = 0; k < 64; ++k) {
        float a0 = Ap[k];
        float a1 = Ap[68 + k];
        float a2 = Ap[136 + k];
        float a3 = Ap[204 + k];
        float w[8];
        #pragma unroll
        for (int j = 0; j < 8; ++j) w[j] = Wp[k * 128 + j];
        #pragma unroll
        for (int j = 0; j < 8; ++j) {
            acc[0][j] = fmaf(a0, w[j], acc[0][j]);
            acc[1][j] = fmaf(a1, w[j], acc[1][j]);
            acc[2][j] = fmaf(a2, w[j], acc[2][j]);
            acc[3][j] = fmaf(a3, w[j], acc[3][j]);
        }
    }

    #pragma unroll
    for (int i = 0; i < 4; ++i) {
        int node = m0 + ty * 4 + i;
        if (node < n_nodes) {
            float s = norm[node];
            unsigned short r[8];
            #pragma unroll
            for (int j = 0; j < 8; ++j) {
                float v = acc[i][j] + b1s[tx * 8 + j];
                v = v > 0.0f ? v : 0.0f;
                r[j] = f2bf(v * s);
            }
            unsigned short* o = H1b + (size_t)node * 128 + tx * 8;
            *(ushort4*)(o)     = make_ushort4(r[0], r[1], r[2], r[3]);
            *(ushort4*)(o + 4) = make_ushort4(r[4], r[5], r[6], r[7]);
        }
    }
}

// y2b[n,64] = bf16(H1b[n,128] @ W2[128,64])
__global__ __launch_bounds__(256) void gemm2b(const unsigned short* __restrict__ H1b,
        const float* __restrict__ W2, unsigned short* __restrict__ y2b, int n_nodes) {
    __shared__ float Ws[128 * 64];
    __shared__ float Hs[64 * 132];
    const int tid = threadIdx.x;
    for (int idx = tid; idx < 128 * 64; idx += 256) Ws[idx] = W2[idx];

    const int m0 = blockIdx.x * 64;
    const ushort4* Hg = (const ushort4*)(H1b + (size_t)m0 * 128);
    #pragma unroll
    for (int i = 0; i < 8; ++i) {
        int idx = tid + i * 256;
        int m = idx >> 5;
        int k4 = (idx & 31) * 4;
        float4 v = make_float4(0.f, 0.f, 0.f, 0.f);
        if (m0 + m < n_nodes) {
            ushort4 u = Hg[idx];
            v.x = bf2f(u.x); v.y = bf2f(u.y); v.z = bf2f(u.z); v.w = bf2f(u.w);
        }
        *(float4*)(Hs + m * 132 + k4) = v;
    }
    __syncthreads();

    const int tx = tid & 15;
    const int ty = tid >> 4;
    float acc[4][4];
    #pragma unroll
    for (int i = 0; i < 4; ++i)
        #pragma unroll
        for (int j = 0; j < 4; ++j) acc[i][j] = 0.0f;

    const float* Ap = Hs + ty * 4 * 132;
    for (int k = 0; k < 128; ++k) {
        float a0 = Ap[k];
        float a1 = Ap[132 + k];
        float a2 = Ap[264 + k];
        float a3 = Ap[396 + k];
        const float4 w = *(const float4*)(Ws + k * 64 + tx * 4);
        acc[0][0] = fmaf(a0, w.x, acc[0][0]); acc[0][1] = fmaf(a0, w.y, acc[0][1]);
        acc[0][2] = fmaf(a0, w.z, acc[0][2]); acc[0][3] = fmaf(a0, w.w, acc[0][3]);
        acc[1][0] = fmaf(a1, w.x, acc[1][0]); acc[1][1] = fmaf(a1, w.y, acc[1][1]);
        acc[1][2] = fmaf(a1, w.z, acc[1][2]); acc[1][3] = fmaf(a1, w.w, acc[1][3]);
        acc[2][0] = fmaf(a2, w.x, acc[2][0]); acc[2][1] = fmaf(a2, w.y, acc[2][1]);
        acc[2][2] = fmaf(a2, w.z, acc[2][2]); acc[2][3] = fmaf(a2, w.w, acc[2][3]);
        acc[3][0] = fmaf(a3, w.x, acc[3][0]); acc[3][1] = fmaf(a3, w.y, acc[3][1]);
        acc[3][2] = fmaf(a3, w.z, acc[3][2]); acc[3][3] = fmaf(a3, w.w, acc[3][3]);
    }

    #pragma unroll
    for (int i = 0; i < 4; ++i) {
        int node = m0 + ty * 4 + i;
        if (node < n_nodes) {
            ushort4 o;
            o.x = f2bf(acc[i][0]); o.y = f2bf(acc[i][1]);
            o.z = f2bf(acc[i][2]); o.w = f2bf(acc[i][3]);
            *(ushort4*)(y2b + (size_t)node * 64 + tx * 4) = o;
        }
    }
}

extern "C" void kernel_launch(void* const* d_in, const int* in_sizes, int n_in,
                              void* d_out, int out_size, void* d_ws, size_t ws_size,
                              hipStream_t stream) {
    const float* h   = (const float*)d_in[0];
    const int*   src = (const int*)d_in[1];
    const int*   dst = (const int*)d_in[2];
    const float* W1  = (const float*)d_in[3];
    const float* b1  = (const float*)d_in[4];
    const float* W2  = (const float*)d_in[5];
    const float* b2  = (const float*)d_in[6];
    float* out = (float*)d_out;

    const int n = in_sizes[0] / 64;
    const int E = in_sizes[1];
    const int nb = (n + 127) >> 7;

    char* p = (char*)d_ws;
    auto alloc = [&](size_t bytes) {
        void* r = (void*)p;
        p += (bytes + 255) & ~(size_t)255;
        return r;
    };
    float* agg1          = (float*)alloc((size_t)n * 64 * 4);
    float* norm_src      = (float*)alloc((size_t)n * 4);
    float* norm_dst      = (float*)alloc((size_t)n * 4);
    int2* node_rng       = (int2*)alloc((size_t)n * 8);
    int* cnt2            = (int*)alloc((size_t)2 * nb * 4);
    int* cnt_s = cnt2;
    int* cnt_d = cnt2 + nb;
    unsigned int* sd     = (unsigned int*)alloc((size_t)nb * CAP * 4);
    unsigned short* xb   = (unsigned short*)alloc((size_t)n * 64 * 2);
    unsigned short* H1b  = (unsigned short*)alloc((size_t)n * 128 * 2);
    unsigned short* y2b  = (unsigned short*)alloc((size_t)n * 64 * 2);
    unsigned short* srt  = (unsigned short*)alloc((size_t)nb * CAP * 2);
    unsigned char* ssb   = (unsigned char*)alloc((size_t)nb * CAP);

    hipMemsetAsync(cnt2, 0, 2 * (size_t)nb * sizeof(int), stream);

    place_direct<<<256, 256, 0, stream>>>(src, dst, cnt_s, cnt_d, ssb, sd, E, nb);
    srcdeg_scale<<<nb, 256, 0, stream>>>(h, ssb, cnt_s, norm_src, xb, n);
    bucket_sort<<<nb, 256, 0, stream>>>(sd, cnt_d, node_rng, srt, norm_dst, n);

    int gb = (n + 3) / 4;
    gather8<<<gb, 256, 0, stream>>>(xb, srt, node_rng, norm_dst, nullptr, agg1, n);

    int tb = (n + 63) / 64;
    gemm1<<<tb, 256, 0, stream>>>(agg1, W1, b1, norm_src, H1b, n);
    gemm2b<<<tb, 256, 0, stream>>>(H1b, W2, y2b, n);

    gather8<<<gb, 256, 0, stream>>>(y2b, srt, node_rng, norm_dst, b2, out, n);
}

// Round 9
// 195.821 us; speedup vs baseline: 2.6878x; 1.0146x over previous
//
#include <hip/hip_runtime.h>

// F0=64, F1=128, F2=64. n<=65536, buckets of 128 nodes, slotted CSR with
// fixed bucket capacity CAP (no hist/scan passes).
// Pipeline: memset(cnt) -> place_direct -> prep(srcdeg+scale+bucketsort) ->
//           gather24(xb->agg1b bf16) -> gemm1(bf16 in -> H1b bf16) ->
//           gemm2b(->y2b bf16) -> gather24(y2b->out f32,+b2)

#define NBMAX 512
#define CAPLOG 12
#define CAP (1 << CAPLOG)

__device__ inline unsigned short f2bf(float f) {
    unsigned int u = __float_as_uint(f);
    unsigned int r = (u + 0x7FFFu + ((u >> 16) & 1u)) >> 16;  // RNE
    return (unsigned short)r;
}
__device__ inline float bf2f_lo(unsigned int u) { return __uint_as_float(u << 16); }
__device__ inline float bf2f_hi(unsigned int u) { return __uint_as_float(u & 0xFFFF0000u); }
__device__ inline float bf2f(unsigned short h) {
    return __uint_as_float((unsigned int)h << 16);
}

// One pass over edges: per-block LDS hist -> one global reservation atomic per
// (block,bucket) -> LDS-cursor scatter into slotted bucket arrays.
// src entry: 1B local id. dst entry: (dst&127)<<25 | src.
__global__ __launch_bounds__(256) void place_direct(const int* __restrict__ src,
        const int* __restrict__ dst, int* __restrict__ cnt_s, int* __restrict__ cnt_d,
        unsigned char* __restrict__ ss, unsigned int* __restrict__ sd,
        int n_edges, int nb) {
    __shared__ int hs[NBMAX], hd[NBMAX], bs[NBMAX], bd[NBMAX];
    for (int i = threadIdx.x; i < nb; i += 256) { hs[i] = 0; hd[i] = 0; }
    __syncthreads();
    int chunk = (n_edges + gridDim.x - 1) / gridDim.x;
    int e0 = blockIdx.x * chunk;
    int e1 = e0 + chunk; if (e1 > n_edges) e1 = n_edges;
    for (int e = e0 + (int)threadIdx.x; e < e1; e += 256) {
        atomicAdd(&hs[src[e] >> 7], 1);
        atomicAdd(&hd[dst[e] >> 7], 1);
    }
    __syncthreads();
    for (int i = threadIdx.x; i < nb; i += 256) {
        int v = hs[i]; bs[i] = v ? atomicAdd(&cnt_s[i], v) : 0; hs[i] = 0;
        v = hd[i];     bd[i] = v ? atomicAdd(&cnt_d[i], v) : 0; hd[i] = 0;
    }
    __syncthreads();
    for (int e = e0 + (int)threadIdx.x; e < e1; e += 256) {
        int s = src[e], d = dst[e];
        int sb = s >> 7, db = d >> 7;
        int ps = bs[sb] + atomicAdd(&hs[sb], 1);
        ss[((size_t)sb << CAPLOG) + ps] = (unsigned char)(s & 127);
        int pd = bd[db] + atomicAdd(&hd[db], 1);
        sd[((size_t)db << CAPLOG) + pd] = ((unsigned int)(d & 127) << 25) | (unsigned int)s;
    }
}

// One block per bucket b:
//  phase 1 (src side): count ss local ids -> norm_src; xb = bf16(h * norm).
//  phase 2 (dst side): 128-bin count of sd -> scan -> node_rng + counting-sorted
//                      srt (u16 src ids) + norm_dst.
__global__ __launch_bounds__(256) void prep(const float* __restrict__ h,
        const unsigned char* __restrict__ ss, const int* __restrict__ cnt_s,
        const unsigned int* __restrict__ sd, const int* __restrict__ cnt_d,
        float* __restrict__ norm_src, unsigned short* __restrict__ xb,
        int2* __restrict__ node_rng, unsigned short* __restrict__ srt,
        float* __restrict__ norm_dst, int n) {
    __shared__ int cnt[128], cur[128];
    __shared__ float nrm[128];
    __shared__ int w0tot;
    const int b = blockIdx.x;
    const int tid = threadIdx.x;

    // ---- phase 1: src degree + scale/cast ----
    if (tid < 128) cnt[tid] = 0;
    __syncthreads();
    {
        int used = cnt_s[b];
        const unsigned char* p = ss + ((size_t)b << CAPLOG);
        for (int i = tid; i < used; i += 256) atomicAdd(&cnt[p[i]], 1);
    }
    __syncthreads();
    if (tid < 128) {
        int c = cnt[tid]; if (c < 1) c = 1;
        float s = 1.0f / sqrtf((float)c);
        nrm[tid] = s;
        int node = (b << 7) + tid;
        if (node < n) norm_src[node] = s;
    }
    __syncthreads();
    {
        int base = b << 7;
        for (int t = tid; t < 128 * 16; t += 256) {
            int r = t >> 4, c4 = (t & 15) << 2;
            int node = base + r;
            if (node < n) {
                float s = nrm[r];
                float4 v = *(const float4*)(h + (size_t)node * 64 + c4);
                ushort4 o;
                o.x = f2bf(v.x * s); o.y = f2bf(v.y * s);
                o.z = f2bf(v.z * s); o.w = f2bf(v.w * s);
                *(ushort4*)(xb + (size_t)node * 64 + c4) = o;
            }
        }
    }
    __syncthreads();

    // ---- phase 2: dst bucket counting sort ----
    if (tid < 128) cnt[tid] = 0;
    __syncthreads();
    int used = cnt_d[b];
    const unsigned int* p = sd + ((size_t)b << CAPLOG);
    for (int i = tid; i < used; i += 256) atomicAdd(&cnt[p[i] >> 25], 1);
    __syncthreads();
    int lane = tid & 63, wid = tid >> 6;
    int v = (tid < 128) ? cnt[tid] : 0;
    int incl = v;
    #pragma unroll
    for (int d = 1; d < 64; d <<= 1) {
        int t = __shfl_up(incl, d, 64);
        if (lane >= d) incl += t;
    }
    if (tid == 63) w0tot = incl;
    __syncthreads();
    if (tid < 128) {
        int excl = incl - v + (wid == 1 ? w0tot : 0);
        cur[tid] = excl;
        int node = (b << 7) + tid;
        if (node < n) {
            int base = b << CAPLOG;
            node_rng[node] = make_int2(base + excl, base + excl + v);
            int c = v; if (c < 1) c = 1;
            norm_dst[node] = 1.0f / sqrtf((float)c);
        }
    }
    __syncthreads();
    for (int i = tid; i < used; i += 256) {
        unsigned int e = p[i];
        int l = (int)(e >> 25);
        int pos = atomicAdd(&cur[l], 1);
        srt[((size_t)b << CAPLOG) + pos] = (unsigned short)(e & 0xFFFFu);
    }
}

// One wave per dst node. 8 lanes x bf16x8 (16B dwordx4) cover the 64-wide row;
// 8 lane-groups x unroll 3 -> 24 edges in flight per round (Poisson(16): 98%
// of nodes finish in ONE dependent round; clamped tail loads are L1 dups).
// f32 accumulate, 3-level shfl_xor reduce; writes bf16 row (mode 1) or f32
// row +bias (mode 0).
__global__ __launch_bounds__(256) void gather24(const unsigned short* __restrict__ xb,
        const unsigned short* __restrict__ srt, const int2* __restrict__ node_rng,
        const float* __restrict__ nrm, const float* __restrict__ bias,
        void* __restrict__ outp, int write_bf, int n_nodes) {
    int node = blockIdx.x * 4 + (threadIdx.x >> 6);
    if (node >= n_nodes) return;
    int lane = threadIdx.x & 63;
    int g  = lane >> 3;         // edge slot 0..7
    int c8 = (lane & 7) * 8;    // column base
    int2 rng = node_rng[node];
    int a0 = rng.x, a1 = rng.y;
    float acc[8];
    #pragma unroll
    for (int j = 0; j < 8; ++j) acc[j] = 0.f;
    for (int base = a0; base < a1; base += 24) {
        #pragma unroll
        for (int u = 0; u < 3; ++u) {
            int ei = base + u * 8 + g;
            int idx = ei < a1 ? ei : a1 - 1;
            float msk = ei < a1 ? 1.0f : 0.0f;
            int s = srt[idx];
            const uint4 v = *(const uint4*)(xb + (size_t)s * 64 + c8);
            acc[0] = fmaf(bf2f_lo(v.x), msk, acc[0]);
            acc[1] = fmaf(bf2f_hi(v.x), msk, acc[1]);
            acc[2] = fmaf(bf2f_lo(v.y), msk, acc[2]);
            acc[3] = fmaf(bf2f_hi(v.y), msk, acc[3]);
            acc[4] = fmaf(bf2f_lo(v.z), msk, acc[4]);
            acc[5] = fmaf(bf2f_hi(v.z), msk, acc[5]);
            acc[6] = fmaf(bf2f_lo(v.w), msk, acc[6]);
            acc[7] = fmaf(bf2f_hi(v.w), msk, acc[7]);
        }
    }
    #pragma unroll
    for (int off = 8; off < 64; off <<= 1) {
        #pragma unroll
        for (int j = 0; j < 8; ++j) acc[j] += __shfl_xor(acc[j], off, 64);
    }
    if (g == 0) {
        float s = nrm[node];
        float r[8];
        #pragma unroll
        for (int j = 0; j < 8; ++j) r[j] = acc[j] * s;
        if (write_bf) {
            unsigned short rb[8];
            #pragma unroll
            for (int j = 0; j < 8; ++j) rb[j] = f2bf(r[j]);
            unsigned short* o = (unsigned short*)outp + (size_t)node * 64 + c8;
            *(ushort4*)(o)     = make_ushort4(rb[0], rb[1], rb[2], rb[3]);
            *(ushort4*)(o + 4) = make_ushort4(rb[4], rb[5], rb[6], rb[7]);
        } else {
            if (bias) {
                #pragma unroll
                for (int j = 0; j < 8; ++j) r[j] += bias[c8 + j];
            }
            float* o = (float*)outp + (size_t)node * 64 + c8;
            *(float4*)(o)     = make_float4(r[0], r[1], r[2], r[3]);
            *(float4*)(o + 4) = make_float4(r[4], r[5], r[6], r[7]);
        }
    }
}

// H1b[n,128] = bf16(relu(Ab[n,64](bf16) @ W1[64,128] + b1) * norm_src[node])
__global__ __launch_bounds__(256) void gemm1(const unsigned short* __restrict__ Ab,
        const float* __restrict__ W1, const float* __restrict__ b1,
        const float* __restrict__ norm, unsigned short* __restrict__ H1b, int n_nodes) {
    __shared__ float Ws[64 * 128];
    __shared__ float As[64 * 68];
    __shared__ float b1s[128];
    const int tid = threadIdx.x;
    for (int idx = tid; idx < 64 * 128; idx += 256) Ws[idx] = W1[idx];
    if (tid < 128) b1s[tid] = b1[tid];

    const int m0 = blockIdx.x * 64;
    const ushort4* Ag = (const ushort4*)(Ab + (size_t)m0 * 64);
    #pragma unroll
    for (int i = 0; i < 4; ++i) {
        int idx = tid + i * 256;
        int m = idx >> 4;
        int k4 = (idx & 15) * 4;
        float4 v = make_float4(0.f, 0.f, 0.f, 0.f);
        if (m0 + m < n_nodes) {
            ushort4 u = Ag[idx];
            v.x = bf2f(u.x); v.y = bf2f(u.y); v.z = bf2f(u.z); v.w = bf2f(u.w);
        }
        *(float4*)(As + m * 68 + k4) = v;
    }
    __syncthreads();

    const int tx = tid & 15;
    const int ty = tid >> 4;
    float acc[4][8];
    #pragma unroll
    for (int i = 0; i < 4; ++i)
        #pragma unroll
        for (int j = 0; j < 8; ++j) acc[i][j] = 0.0f;

    const float* Ap = As + ty * 4 * 68;
    const float* Wp = Ws + tx * 8;
    for (int k = 0; k < 64; ++k) {
        float a0 = Ap[k];
        float a1 = Ap[68 + k];
        float a2 = Ap[136 + k];
        float a3 = Ap[204 + k];
        float w[8];
        #pragma unroll
        for (int j = 0; j < 8; ++j) w[j] = Wp[k * 128 + j];
        #pragma unroll
        for (int j = 0; j < 8; ++j) {
            acc[0][j] = fmaf(a0, w[j], acc[0][j]);
            acc[1][j] = fmaf(a1, w[j], acc[1][j]);
            acc[2][j] = fmaf(a2, w[j], acc[2][j]);
            acc[3][j] = fmaf(a3, w[j], acc[3][j]);
        }
    }

    #pragma unroll
    for (int i = 0; i < 4; ++i) {
        int node = m0 + ty * 4 + i;
        if (node < n_nodes) {
            float s = norm[node];
            unsigned short r[8];
            #pragma unroll
            for (int j = 0; j < 8; ++j) {
                float v = acc[i][j] + b1s[tx * 8 + j];
                v = v > 0.0f ? v : 0.0f;
                r[j] = f2bf(v * s);
            }
            unsigned short* o = H1b + (size_t)node * 128 + tx * 8;
            *(ushort4*)(o)     = make_ushort4(r[0], r[1], r[2], r[3]);
            *(ushort4*)(o + 4) = make_ushort4(r[4], r[5], r[6], r[7]);
        }
    }
}

// y2b[n,64] = bf16(H1b[n,128] @ W2[128,64])
__global__ __launch_bounds__(256) void gemm2b(const unsigned short* __restrict__ H1b,
        const float* __restrict__ W2, unsigned short* __restrict__ y2b, int n_nodes) {
    __shared__ float Ws[128 * 64];
    __shared__ float Hs[64 * 132];
    const int tid = threadIdx.x;
    for (int idx = tid; idx < 128 * 64; idx += 256) Ws[idx] = W2[idx];

    const int m0 = blockIdx.x * 64;
    const ushort4* Hg = (const ushort4*)(H1b + (size_t)m0 * 128);
    #pragma unroll
    for (int i = 0; i < 8; ++i) {
        int idx = tid + i * 256;
        int m = idx >> 5;
        int k4 = (idx & 31) * 4;
        float4 v = make_float4(0.f, 0.f, 0.f, 0.f);
        if (m0 + m < n_nodes) {
            ushort4 u = Hg[idx];
            v.x = bf2f(u.x); v.y = bf2f(u.y); v.z = bf2f(u.z); v.w = bf2f(u.w);
        }
        *(float4*)(Hs + m * 132 + k4) = v;
    }
    __syncthreads();

    const int tx = tid & 15;
    const int ty = tid >> 4;
    float acc[4][4];
    #pragma unroll
    for (int i = 0; i < 4; ++i)
        #pragma unroll
        for (int j = 0; j < 4; ++j) acc[i][j] = 0.0f;

    const float* Ap = Hs + ty * 4 * 132;
    for (int k = 0; k < 128; ++k) {
        float a0 = Ap[k];
        float a1 = Ap[132 + k];
        float a2 = Ap[264 + k];
        float a3 = Ap[396 + k];
        const float4 w = *(const float4*)(Ws + k * 64 + tx * 4);
        acc[0][0] = fmaf(a0, w.x, acc[0][0]); acc[0][1] = fmaf(a0, w.y, acc[0][1]);
        acc[0][2] = fmaf(a0, w.z, acc[0][2]); acc[0][3] = fmaf(a0, w.w, acc[0][3]);
        acc[1][0] = fmaf(a1, w.x, acc[1][0]); acc[1][1] = fmaf(a1, w.y, acc[1][1]);
        acc[1][2] = fmaf(a1, w.z, acc[1][2]); acc[1][3] = fmaf(a1, w.w, acc[1][3]);
        acc[2][0] = fmaf(a2, w.x, acc[2][0]); acc[2][1] = fmaf(a2, w.y, acc[2][1]);
        acc[2][2] = fmaf(a2, w.z, acc[2][2]); acc[2][3] = fmaf(a2, w.w, acc[2][3]);
        acc[3][0] = fmaf(a3, w.x, acc[3][0]); acc[3][1] = fmaf(a3, w.y, acc[3][1]);
        acc[3][2] = fmaf(a3, w.z, acc[3][2]); acc[3][3] = fmaf(a3, w.w, acc[3][3]);
    }

    #pragma unroll
    for (int i = 0; i < 4; ++i) {
        int node = m0 + ty * 4 + i;
        if (node < n_nodes) {
            ushort4 o;
            o.x = f2bf(acc[i][0]); o.y = f2bf(acc[i][1]);
            o.z = f2bf(acc[i][2]); o.w = f2bf(acc[i][3]);
            *(ushort4*)(y2b + (size_t)node * 64 + tx * 4) = o;
        }
    }
}

extern "C" void kernel_launch(void* const* d_in, const int* in_sizes, int n_in,
                              void* d_out, int out_size, void* d_ws, size_t ws_size,
                              hipStream_t stream) {
    const float* h   = (const float*)d_in[0];
    const int*   src = (const int*)d_in[1];
    const int*   dst = (const int*)d_in[2];
    const float* W1  = (const float*)d_in[3];
    const float* b1  = (const float*)d_in[4];
    const float* W2  = (const float*)d_in[5];
    const float* b2  = (const float*)d_in[6];
    float* out = (float*)d_out;

    const int n = in_sizes[0] / 64;
    const int E = in_sizes[1];
    const int nb = (n + 127) >> 7;

    char* p = (char*)d_ws;
    auto alloc = [&](size_t bytes) {
        void* r = (void*)p;
        p += (bytes + 255) & ~(size_t)255;
        return r;
    };
    float* norm_src      = (float*)alloc((size_t)n * 4);
    float* norm_dst      = (float*)alloc((size_t)n * 4);
    int2* node_rng       = (int2*)alloc((size_t)n * 8);
    int* cnt2            = (int*)alloc((size_t)2 * nb * 4);
    int* cnt_s = cnt2;
    int* cnt_d = cnt2 + nb;
    unsigned int* sd     = (unsigned int*)alloc((size_t)nb * CAP * 4);
    unsigned short* xb   = (unsigned short*)alloc((size_t)n * 64 * 2);
    unsigned short* agg1b= (unsigned short*)alloc((size_t)n * 64 * 2);
    unsigned short* H1b  = (unsigned short*)alloc((size_t)n * 128 * 2);
    unsigned short* y2b  = (unsigned short*)alloc((size_t)n * 64 * 2);
    unsigned short* srt  = (unsigned short*)alloc((size_t)nb * CAP * 2);
    unsigned char* ssb   = (unsigned char*)alloc((size_t)nb * CAP);

    hipMemsetAsync(cnt2, 0, 2 * (size_t)nb * sizeof(int), stream);

    place_direct<<<256, 256, 0, stream>>>(src, dst, cnt_s, cnt_d, ssb, sd, E, nb);
    prep<<<nb, 256, 0, stream>>>(h, ssb, cnt_s, sd, cnt_d, norm_src, xb,
                                 node_rng, srt, norm_dst, n);

    int gb = (n + 3) / 4;
    gather24<<<gb, 256, 0, stream>>>(xb, srt, node_rng, norm_dst, nullptr,
                                     (void*)agg1b, 1, n);

    int tb = (n + 63) / 64;
    gemm1<<<tb, 256, 0, stream>>>(agg1b, W1, b1, norm_src, H1b, n);
    gemm2b<<<tb, 256, 0, stream>>>(H1b, W2, y2b, n);

    gather24<<<gb, 256, 0, stream>>>(y2b, srt, node_rng, norm_dst, b2,
                                     (void*)out, 0, n);
}